// Round 2
// baseline (73.407 us; speedup 1.0000x reference)
//
#include <hip/hip_runtime.h>

#define KK 5
#define RR 2
#define N_ 2
#define C_ 256
#define H_ 128
#define W_ 128
#define H2 256
#define W2 256
#define TH 16
#define TW 16
#define CCHUNK 16
#define PH 20
#define PW 20
#define PHPW (PH*PW)          // 400
#define CSTR 20               // padded channel stride (words); gcd(20,32)=4 -> even bank-group spread
#define HW (H_*W_)

__global__ __launch_bounds__(256, 4) void carafe_kernel(
    const float* __restrict__ feat,
    const float* __restrict__ masks,
    float* __restrict__ out)
{
    // patch[p][c]: channel-interleaved so 4 channels read as one ds_read_b128.
    __shared__ float patch[PHPW * CSTR];   // 400*20*4 = 32000 B

    const int tid = threadIdx.x;
    const int tx = tid & 15;
    const int ty = tid >> 4;
    const int bx = blockIdx.x & 7;     // W_/TW = 8
    const int by = blockIdx.x >> 3;    // H_/TH = 8
    const int c0 = blockIdx.y * CCHUNK;
    const int n  = blockIdx.z;

    const int i0 = by * TH + ty;
    const int j0 = bx * TW + tx;
    const int gy0 = by * TH - RR;
    const int gx0 = bx * TW - RR;

    // ---- stage all CCHUNK channels' 20x20 halo patches, once ----
    const float* fbase = feat + (size_t)(n * C_ + c0) * HW;
    #pragma unroll
    for (int r = 0; r < (CCHUNK * PHPW) / 256; ++r) {   // 25 iterations, exact
        const int idx = tid + r * 256;
        const int c   = idx / PHPW;
        const int p   = idx - c * PHPW;
        const int py  = p / PW;
        const int px  = p - py * PW;
        const int gy  = gy0 + py;
        const int gx  = gx0 + px;
        float v = 0.f;
        if ((unsigned)gy < (unsigned)H_ && (unsigned)gx < (unsigned)W_)
            v = fbase[c * HW + gy * W_ + gx];
        patch[p * CSTR + c] = v;
    }
    __syncthreads();

    // ---- k-outer / channel-inner: 4 mask values per k, reused across 16 channels ----
    float acc[CCHUNK][2][2] = {};
    const float* mb = masks + ((size_t)n * (KK * KK) * H2 + (size_t)(2 * i0)) * W2 + 2 * j0;
    const int pbase = (ty * PW + tx) * CSTR;

    #pragma unroll
    for (int dy = 0; dy < KK; ++dy) {
        #pragma unroll
        for (int dx = 0; dx < KK; ++dx) {
            const int k = dy * KK + dx;
            const float* mk = mb + (size_t)k * (H2 * W2);
            const float2 m0 = *reinterpret_cast<const float2*>(mk);
            const float2 m1 = *reinterpret_cast<const float2*>(mk + W2);
            const int off = pbase + (dy * PW + dx) * CSTR;   // compile-time delta from pbase
            #pragma unroll
            for (int cg = 0; cg < CCHUNK / 4; ++cg) {
                const float4 v = *reinterpret_cast<const float4*>(&patch[off + 4 * cg]);
                acc[4*cg+0][0][0] += v.x * m0.x;  acc[4*cg+0][0][1] += v.x * m0.y;
                acc[4*cg+0][1][0] += v.x * m1.x;  acc[4*cg+0][1][1] += v.x * m1.y;
                acc[4*cg+1][0][0] += v.y * m0.x;  acc[4*cg+1][0][1] += v.y * m0.y;
                acc[4*cg+1][1][0] += v.y * m1.x;  acc[4*cg+1][1][1] += v.y * m1.y;
                acc[4*cg+2][0][0] += v.z * m0.x;  acc[4*cg+2][0][1] += v.z * m0.y;
                acc[4*cg+2][1][0] += v.z * m1.x;  acc[4*cg+2][1][1] += v.z * m1.y;
                acc[4*cg+3][0][0] += v.w * m0.x;  acc[4*cg+3][0][1] += v.w * m0.y;
                acc[4*cg+3][1][0] += v.w * m1.x;  acc[4*cg+3][1][1] += v.w * m1.y;
            }
        }
    }

    // ---- store: 16 channels x 2x2 quad, float2 rows ----
    #pragma unroll
    for (int c = 0; c < CCHUNK; ++c) {
        float* ob = out + ((size_t)(n * C_ + c0 + c) * H2 + (size_t)(2 * i0)) * W2 + 2 * j0;
        *reinterpret_cast<float2*>(ob)      = make_float2(acc[c][0][0], acc[c][0][1]);
        *reinterpret_cast<float2*>(ob + W2) = make_float2(acc[c][1][0], acc[c][1][1]);
    }
}

extern "C" void kernel_launch(void* const* d_in, const int* in_sizes, int n_in,
                              void* d_out, int out_size, void* d_ws, size_t ws_size,
                              hipStream_t stream) {
    const float* feat  = (const float*)d_in[0];
    const float* masks = (const float*)d_in[1];
    float* out = (float*)d_out;

    dim3 grid((W_ / TW) * (H_ / TH),   // 64 spatial tiles
              C_ / CCHUNK,             // 16 channel chunks
              N_);                     // 2 batch
    carafe_kernel<<<grid, dim3(256), 0, stream>>>(feat, masks, out);
}

// Round 3
// 65.807 us; speedup vs baseline: 1.1155x; 1.1155x over previous
//
#include <hip/hip_runtime.h>

#define KK 5
#define RR 2
#define N_ 2
#define C_ 256
#define H_ 128
#define W_ 128
#define H2 256
#define W2 256
#define TH 16
#define TW 16
#define CCHUNK 8
#define PH 20
#define PW 20
#define PHPW (PH*PW)          // 400
#define CSTR 12               // 8 channels + 4 pad words; 12*tx mod 32 covers all 8 bank-groups
#define HW (H_*W_)

__global__ __launch_bounds__(256) void carafe_kernel(
    const float* __restrict__ feat,
    const float* __restrict__ masks,
    float* __restrict__ out)
{
    // patch[p][c]: 8 channels per pixel, read as two ds_read_b128.
    __shared__ float patch[PHPW * CSTR];   // 400*12*4 = 19200 B

    const int tid = threadIdx.x;
    const int tx = tid & 15;
    const int ty = tid >> 4;
    const int bx = blockIdx.x & 7;     // W_/TW = 8
    const int by = blockIdx.x >> 3;    // H_/TH = 8
    const int c0 = blockIdx.y * CCHUNK;
    const int n  = blockIdx.z;

    const int i0 = by * TH + ty;
    const int j0 = bx * TW + tx;
    const int gy0 = by * TH - RR;
    const int gx0 = bx * TW - RR;

    // ---- stage CCHUNK channels' 20x20 halo patches (3200 words, 13 rounds) ----
    const float* fbase = feat + (size_t)(n * C_ + c0) * HW;
    #pragma unroll
    for (int r = 0; r < 13; ++r) {
        const int idx = tid + r * 256;
        if (idx < CCHUNK * PHPW) {
            const int c   = idx / PHPW;
            const int p   = idx - c * PHPW;
            const int py  = p / PW;
            const int px  = p - py * PW;
            const int gy  = gy0 + py;
            const int gx  = gx0 + px;
            float v = 0.f;
            if ((unsigned)gy < (unsigned)H_ && (unsigned)gx < (unsigned)W_)
                v = fbase[c * HW + gy * W_ + gx];
            patch[p * CSTR + c] = v;
        }
    }
    __syncthreads();

    // ---- k-outer / channel-inner ----
    float acc[CCHUNK][2][2] = {};
    const float* mb = masks + ((size_t)n * (KK * KK) * H2 + (size_t)(2 * i0)) * W2 + 2 * j0;
    const int pbase = (ty * PW + tx) * CSTR;

    #pragma unroll
    for (int dy = 0; dy < KK; ++dy) {
        #pragma unroll
        for (int dx = 0; dx < KK; ++dx) {
            const int k = dy * KK + dx;
            const float* mk = mb + (size_t)k * (H2 * W2);
            const float2 m0 = *reinterpret_cast<const float2*>(mk);
            const float2 m1 = *reinterpret_cast<const float2*>(mk + W2);
            const int off = pbase + (dy * PW + dx) * CSTR;
            const float4 v0 = *reinterpret_cast<const float4*>(&patch[off]);
            const float4 v1 = *reinterpret_cast<const float4*>(&patch[off + 4]);

            acc[0][0][0] += v0.x * m0.x;  acc[0][0][1] += v0.x * m0.y;
            acc[0][1][0] += v0.x * m1.x;  acc[0][1][1] += v0.x * m1.y;
            acc[1][0][0] += v0.y * m0.x;  acc[1][0][1] += v0.y * m0.y;
            acc[1][1][0] += v0.y * m1.x;  acc[1][1][1] += v0.y * m1.y;
            acc[2][0][0] += v0.z * m0.x;  acc[2][0][1] += v0.z * m0.y;
            acc[2][1][0] += v0.z * m1.x;  acc[2][1][1] += v0.z * m1.y;
            acc[3][0][0] += v0.w * m0.x;  acc[3][0][1] += v0.w * m0.y;
            acc[3][1][0] += v0.w * m1.x;  acc[3][1][1] += v0.w * m1.y;
            acc[4][0][0] += v1.x * m0.x;  acc[4][0][1] += v1.x * m0.y;
            acc[4][1][0] += v1.x * m1.x;  acc[4][1][1] += v1.x * m1.y;
            acc[5][0][0] += v1.y * m0.x;  acc[5][0][1] += v1.y * m0.y;
            acc[5][1][0] += v1.y * m1.x;  acc[5][1][1] += v1.y * m1.y;
            acc[6][0][0] += v1.z * m0.x;  acc[6][0][1] += v1.z * m0.y;
            acc[6][1][0] += v1.z * m1.x;  acc[6][1][1] += v1.z * m1.y;
            acc[7][0][0] += v1.w * m0.x;  acc[7][0][1] += v1.w * m0.y;
            acc[7][1][0] += v1.w * m1.x;  acc[7][1][1] += v1.w * m1.y;
        }
    }

    // ---- store: 8 channels x 2x2 quad, float2 rows ----
    #pragma unroll
    for (int c = 0; c < CCHUNK; ++c) {
        float* ob = out + ((size_t)(n * C_ + c0 + c) * H2 + (size_t)(2 * i0)) * W2 + 2 * j0;
        *reinterpret_cast<float2*>(ob)      = make_float2(acc[c][0][0], acc[c][0][1]);
        *reinterpret_cast<float2*>(ob + W2) = make_float2(acc[c][1][0], acc[c][1][1]);
    }
}

extern "C" void kernel_launch(void* const* d_in, const int* in_sizes, int n_in,
                              void* d_out, int out_size, void* d_ws, size_t ws_size,
                              hipStream_t stream) {
    const float* feat  = (const float*)d_in[0];
    const float* masks = (const float*)d_in[1];
    float* out = (float*)d_out;

    dim3 grid((W_ / TW) * (H_ / TH),   // 64 spatial tiles
              C_ / CCHUNK,             // 32 channel chunks
              N_);                     // 2 batch
    carafe_kernel<<<grid, dim3(256), 0, stream>>>(feat, masks, out);
}

// Round 4
// 60.104 us; speedup vs baseline: 1.2213x; 1.0949x over previous
//
#include <hip/hip_runtime.h>

#define KK 5
#define RR 2
#define N_ 2
#define C_ 256
#define H_ 128
#define W_ 128
#define H2 256
#define W2 256
#define TH 16
#define TW 16
#define CCHUNK 16
#define PH 20
#define PW 20
#define PHPW 400
#define CSTR 20              // 16 channels + 4 pad words; gcd(20,32)=4 -> uniform bank-group spread
#define HW (H_*W_)
#define DEPTH 2              // mask prefetch ring depth

__global__ __launch_bounds__(256) void carafe_kernel(
    const float* __restrict__ feat,
    const float* __restrict__ masks,
    float* __restrict__ out)
{
    // patch[p][c]: 16 channels per pixel -> four ds_read_b128 per (pixel,k).
    __shared__ float patch[PHPW * CSTR];   // 400*20*4 = 32000 B

    const int tid = threadIdx.x;
    const int tx = tid & 15;
    const int ty = tid >> 4;
    const int bx = blockIdx.x & 7;     // W_/TW = 8
    const int by = blockIdx.x >> 3;    // H_/TH = 8
    const int c0 = blockIdx.y * CCHUNK;
    const int n  = blockIdx.z;

    const int i0 = by * TH + ty;
    const int j0 = bx * TW + tx;
    const int gy0 = by * TH - RR;
    const int gx0 = bx * TW - RR;

    // ---- stage 16 channels' 20x20 halo patches: 6400 words = 25 exact rounds ----
    const float* fbase = feat + (size_t)(n * C_ + c0) * HW;
    #pragma unroll
    for (int r = 0; r < 25; ++r) {
        const int idx = tid + r * 256;
        const int c   = idx / PHPW;
        const int p   = idx - c * PHPW;
        const int py  = p / PW;
        const int px  = p - py * PW;
        const int gy  = gy0 + py;
        const int gx  = gx0 + px;
        float v = 0.f;
        if ((unsigned)gy < (unsigned)H_ && (unsigned)gx < (unsigned)W_)
            v = fbase[c * HW + gy * W_ + gx];
        patch[p * CSTR + c] = v;
    }
    __syncthreads();

    // ---- k-outer / channel-inner with depth-2 mask prefetch ring ----
    float acc[CCHUNK][2][2] = {};
    const float* mb = masks + ((size_t)n * (KK * KK) * H2 + (size_t)(2 * i0)) * W2 + 2 * j0;
    const int pbase = (ty * PW + tx) * CSTR;

    float2 q0[DEPTH], q1[DEPTH];
    #pragma unroll
    for (int t = 0; t < DEPTH; ++t) {
        q0[t] = *reinterpret_cast<const float2*>(mb + (size_t)t * (H2 * W2));
        q1[t] = *reinterpret_cast<const float2*>(mb + (size_t)t * (H2 * W2) + W2);
    }

    #pragma unroll
    for (int k = 0; k < KK * KK; ++k) {
        const float2 m0 = q0[k % DEPTH];   // static index after unroll
        const float2 m1 = q1[k % DEPTH];
        if (k + DEPTH < KK * KK) {
            q0[k % DEPTH] = *reinterpret_cast<const float2*>(mb + (size_t)(k + DEPTH) * (H2 * W2));
            q1[k % DEPTH] = *reinterpret_cast<const float2*>(mb + (size_t)(k + DEPTH) * (H2 * W2) + W2);
        }
        const int dy = k / KK;
        const int dx = k - KK * dy;
        const int off = pbase + (dy * PW + dx) * CSTR;
        const float4 v0 = *reinterpret_cast<const float4*>(&patch[off]);
        const float4 v1 = *reinterpret_cast<const float4*>(&patch[off + 4]);
        const float4 v2 = *reinterpret_cast<const float4*>(&patch[off + 8]);
        const float4 v3 = *reinterpret_cast<const float4*>(&patch[off + 12]);
        const float va[16] = { v0.x, v0.y, v0.z, v0.w,  v1.x, v1.y, v1.z, v1.w,
                               v2.x, v2.y, v2.z, v2.w,  v3.x, v3.y, v3.z, v3.w };
        #pragma unroll
        for (int c = 0; c < 16; ++c) {
            acc[c][0][0] += va[c] * m0.x;  acc[c][0][1] += va[c] * m0.y;
            acc[c][1][0] += va[c] * m1.x;  acc[c][1][1] += va[c] * m1.y;
        }
    }

    // ---- store: 16 channels x 2x2 quad, float2 rows ----
    #pragma unroll
    for (int c = 0; c < CCHUNK; ++c) {
        float* ob = out + ((size_t)(n * C_ + c0 + c) * H2 + (size_t)(2 * i0)) * W2 + 2 * j0;
        *reinterpret_cast<float2*>(ob)      = make_float2(acc[c][0][0], acc[c][0][1]);
        *reinterpret_cast<float2*>(ob + W2) = make_float2(acc[c][1][0], acc[c][1][1]);
    }
}

extern "C" void kernel_launch(void* const* d_in, const int* in_sizes, int n_in,
                              void* d_out, int out_size, void* d_ws, size_t ws_size,
                              hipStream_t stream) {
    const float* feat  = (const float*)d_in[0];
    const float* masks = (const float*)d_in[1];
    float* out = (float*)d_out;

    dim3 grid((W_ / TW) * (H_ / TH),   // 64 spatial tiles
              C_ / CCHUNK,             // 16 channel chunks
              N_);                     // 2 batch
    carafe_kernel<<<grid, dim3(256), 0, stream>>>(feat, masks, out);
}

// Round 5
// 53.515 us; speedup vs baseline: 1.3717x; 1.1231x over previous
//
#include <hip/hip_runtime.h>

#define KK 5
#define RR 2
#define N_ 2
#define C_ 256
#define H_ 128
#define W_ 128
#define H2 256
#define W2 256
#define TH 16
#define TW 16
#define CCHUNK 16
#define PH 20
#define PW 20
#define PHPW 400             // pixels per halo patch
#define HW (H_*W_)
#define HW2 (H2*W2)
#define DEPTH 4              // mask prefetch ring depth

__global__ __launch_bounds__(256) void carafe_kernel(
    const float* __restrict__ feat,
    const float* __restrict__ masks,
    float* __restrict__ out)
{
    // Channel-group-planar layout: word = G*1600 + p*4 + t holds channel 4G+t
    // at pixel p. Both ds_write_b128 (staging) and ds_read_b128 (k-loop) land
    // exactly 8 words/bank across 64 lanes = conflict-free throughput floor.
    __shared__ float patch[4 * PHPW * 4];   // 6400 words = 25600 B

    const int tid = threadIdx.x;
    const int tx = tid & 15;
    const int ty = tid >> 4;
    const int bx = blockIdx.x & 7;     // W_/TW = 8
    const int by = blockIdx.x >> 3;    // H_/TH = 8
    const int c0 = blockIdx.y * CCHUNK;
    const int n  = blockIdx.z;

    const int i0 = by * TH + ty;
    const int j0 = bx * TW + tx;
    const int gy0 = by * TH - RR;
    const int gx0 = bx * TW - RR;

    // ---- mask ring preload FIRST: latency hides under staging + barrier ----
    const float* mb = masks + ((size_t)n * (KK * KK) * H2 + (size_t)(2 * i0)) * W2 + 2 * j0;
    float2 q0[DEPTH], q1[DEPTH];
    #pragma unroll
    for (int t = 0; t < DEPTH; ++t) {
        q0[t] = *reinterpret_cast<const float2*>(mb + (size_t)t * HW2);
        q1[t] = *reinterpret_cast<const float2*>(mb + (size_t)t * HW2 + W2);
    }

    // ---- stage: 1600 quad-slots, thread -> (G = idx/400, p = idx%400) ----
    // 4 coalesced global dword streams (channels 4G..4G+3) -> one ds_write_b128.
    const float* fbase = feat + (size_t)(n * C_ + c0) * HW;
    #pragma unroll
    for (int r = 0; r < 7; ++r) {
        const int idx = tid + r * 256;
        if (idx < 4 * PHPW) {
            const int G  = idx / PHPW;
            const int p  = idx - G * PHPW;
            const int py = p / PW;
            const int px = p - py * PW;
            const int gy = gy0 + py;
            const int gx = gx0 + px;
            float4 v = make_float4(0.f, 0.f, 0.f, 0.f);
            if ((unsigned)gy < (unsigned)H_ && (unsigned)gx < (unsigned)W_) {
                const float* fp = fbase + (4 * G) * HW + gy * W_ + gx;
                v.x = fp[0];
                v.y = fp[HW];
                v.z = fp[2 * HW];
                v.w = fp[3 * HW];
            }
            *reinterpret_cast<float4*>(&patch[G * 1600 + p * 4]) = v;
        }
    }
    __syncthreads();

    // ---- k-outer / channel-inner with depth-4 mask ring ----
    float acc[CCHUNK][2][2] = {};
    const int p0 = ty * PW + tx;

    #pragma unroll
    for (int k = 0; k < KK * KK; ++k) {
        const float2 m0 = q0[k % DEPTH];   // static index after unroll
        const float2 m1 = q1[k % DEPTH];
        if (k + DEPTH < KK * KK) {
            q0[k % DEPTH] = *reinterpret_cast<const float2*>(mb + (size_t)(k + DEPTH) * HW2);
            q1[k % DEPTH] = *reinterpret_cast<const float2*>(mb + (size_t)(k + DEPTH) * HW2 + W2);
        }
        const int dy = k / KK;
        const int dx = k - KK * dy;
        const int P  = p0 + dy * PW + dx;
        const float4 v0 = *reinterpret_cast<const float4*>(&patch[P * 4]);
        const float4 v1 = *reinterpret_cast<const float4*>(&patch[1600 + P * 4]);
        const float4 v2 = *reinterpret_cast<const float4*>(&patch[3200 + P * 4]);
        const float4 v3 = *reinterpret_cast<const float4*>(&patch[4800 + P * 4]);
        const float va[16] = { v0.x, v0.y, v0.z, v0.w,  v1.x, v1.y, v1.z, v1.w,
                               v2.x, v2.y, v2.z, v2.w,  v3.x, v3.y, v3.z, v3.w };
        #pragma unroll
        for (int c = 0; c < 16; ++c) {
            acc[c][0][0] += va[c] * m0.x;  acc[c][0][1] += va[c] * m0.y;
            acc[c][1][0] += va[c] * m1.x;  acc[c][1][1] += va[c] * m1.y;
        }
    }

    // ---- store: 16 channels x 2x2 quad, float2 rows ----
    #pragma unroll
    for (int c = 0; c < CCHUNK; ++c) {
        float* ob = out + ((size_t)(n * C_ + c0 + c) * H2 + (size_t)(2 * i0)) * W2 + 2 * j0;
        *reinterpret_cast<float2*>(ob)      = make_float2(acc[c][0][0], acc[c][0][1]);
        *reinterpret_cast<float2*>(ob + W2) = make_float2(acc[c][1][0], acc[c][1][1]);
    }
}

extern "C" void kernel_launch(void* const* d_in, const int* in_sizes, int n_in,
                              void* d_out, int out_size, void* d_ws, size_t ws_size,
                              hipStream_t stream) {
    const float* feat  = (const float*)d_in[0];
    const float* masks = (const float*)d_in[1];
    float* out = (float*)d_out;

    dim3 grid((W_ / TW) * (H_ / TH),   // 64 spatial tiles
              C_ / CCHUNK,             // 16 channel chunks
              N_);                     // 2 batch
    carafe_kernel<<<grid, dim3(256), 0, stream>>>(feat, masks, out);
}